// Round 1
// 459.398 us; speedup vs baseline: 1.0016x; 1.0016x over previous
//
#include <hip/hip_runtime.h>
#include <math.h>

#define W 4
#define NUM_HEADS 32
#define HEAD_SIZE 128
#define G 8            // kv heads
#define QPG 4          // query heads per kv head
#define BLOCK_SZ 16
#define NUM_BLOCKS 1024
#define MAX_BLOCKS 32
#define S 32           // num seqs
#define SPLIT 2        // blocks per (w,s,g)
#define NPART (W * SPLIT)   // partials per (s,g) for the reduce
#define SCALE 0.08838834764831845f  // 1/sqrt(128)
#define NEG_BIG (-1e30f)
#define L2E 1.4426950408889634f
#define K1L2E (SCALE * L2E)          // folds the logit scale into exp2
#define RESCALE_MARGIN 4.0f          // deferred-max headroom: p <= e^MARGIN

// Per-block elems in the paged cache: [block][g][slot][d]
#define BLK_STRIDE (G * BLOCK_SZ * HEAD_SIZE)   // 16384
#define WG_STRIDE  (NUM_BLOCKS * BLK_STRIDE)    // per-w elems

// DPP-fused shuffle+add: v_add_f32 with a DPP-moved source (1 VALU op when the
// backend folds the mov_dpp, vs ds_swizzle(LDS pipe) + v_add before).
template <int CTRL>
__device__ __forceinline__ float dpp_fold(float x) {
    const int y = __builtin_amdgcn_update_dpp(0, __float_as_int(x), CTRL, 0xF, 0xF, true);
    return x + __int_as_float(y);
}

// All-lanes sum across a 32-lane half: 4 DPP stages + one xor-16 swizzle.
// (mirror pairings are valid reduce involutions once the finer stages are done)
__device__ __forceinline__ float half_allsum(float x) {
    x = dpp_fold<0xB1>(x);    // quad_perm [1,0,3,2] : xor 1
    x = dpp_fold<0x4E>(x);    // quad_perm [2,3,0,1] : xor 2
    x = dpp_fold<0x141>(x);   // row_half_mirror     : folds across 4-lane boundary
    x = dpp_fold<0x140>(x);   // row_mirror          : folds across 8-lane boundary
    x += __shfl_xor(x, 16);   // cross 16 (stays within the 32-lane half)
    return x;
}

// Kernel 1: one block per (w,s,g,p). 256 threads = 8 half-wave accumulators;
// global half id h = accid + 8*p takes tokens t ≡ h (mod 16), 2 tokens/iter.
// Deferred-max softmax: one running m per half, rescale only when the tile max
// exceeds it (rare, wave-half-uniform). Writes unnormalized acc + (m,e) partials.
__global__ __launch_bounds__(256, 5)
void pa_partial_kernel(const float* __restrict__ query,
                       const float* __restrict__ key_cache,
                       const float* __restrict__ value_cache,
                       const int* __restrict__ block_tables,
                       const int* __restrict__ context_lens,
                       float* __restrict__ acc_ws,
                       float* __restrict__ m_ws,
                       float* __restrict__ e_ws)
{
    int bx = blockIdx.x;                 // ((w*S + s)*G + g)*SPLIT + p
    const int p = bx % SPLIT; bx /= SPLIT;
    const int g = bx % G;     bx /= G;
    const int s = bx % S;
    const int w = bx / S;

    const int tid   = threadIdx.x;
    const int accid = tid >> 5;          // 0..7
    const int lane  = tid & 31;
    const int d0    = lane * 4;
    const int h     = accid + 8 * p;     // global half id 0..15

    __shared__ int   bt_lds[MAX_BLOCKS];
    __shared__ float sm_m[8];            // one running max per half (shared across qi)
    __shared__ float sm_e[8][QPG];
    __shared__ float sm_acc[8][QPG][HEAD_SIZE];

    if (tid < MAX_BLOCKS)
        bt_lds[tid] = block_tables[((size_t)w * S + s) * MAX_BLOCKS + tid];
    __syncthreads();

    float4 qf[QPG];
#pragma unroll
    for (int qi = 0; qi < QPG; ++qi)
        qf[qi] = *reinterpret_cast<const float4*>(
            query + ((size_t)s * NUM_HEADS + g * QPG + qi) * HEAD_SIZE + d0);

    const int ctx = context_lens[w * S + s];
    const float* kbase = key_cache   + (size_t)w * WG_STRIDE + (size_t)g * BLOCK_SZ * HEAD_SIZE;
    const float* vbase = value_cache + (size_t)w * WG_STRIDE + (size_t)g * BLOCK_SZ * HEAD_SIZE;

    float m_run = NEG_BIG;
    float bexp  = 0.f;   // = -m_run*L2E; set on first rescale (iter 0 always triggers)
    float e_i[QPG];
    float4 acc[QPG];
#pragma unroll
    for (int qi = 0; qi < QPG; ++qi) {
        e_i[qi] = 0.f;
        acc[qi] = make_float4(0.f, 0.f, 0.f, 0.f);
    }

    int t = h;
    for (; t + 16 < ctx; t += 32) {      // both tokens valid: no per-iter masking
        const int slot = (t & 15) * HEAD_SIZE + d0;
        const int off1 = bt_lds[t >> 4] * BLK_STRIDE + slot;
        const int off2 = bt_lds[(t >> 4) + 1] * BLK_STRIDE + slot;
        const float4 k1 = *reinterpret_cast<const float4*>(kbase + off1);
        const float4 k2 = *reinterpret_cast<const float4*>(kbase + off2);
        const float4 v1 = *reinterpret_cast<const float4*>(vbase + off1);
        const float4 v2 = *reinterpret_cast<const float4*>(vbase + off2);

        float dA[QPG], dB[QPG];
#pragma unroll
        for (int qi = 0; qi < QPG; ++qi) {
            dA[qi] = qf[qi].x*k1.x + qf[qi].y*k1.y + qf[qi].z*k1.z + qf[qi].w*k1.w;
            dB[qi] = qf[qi].x*k2.x + qf[qi].y*k2.y + qf[qi].z*k2.z + qf[qi].w*k2.w;
        }
#pragma unroll
        for (int qi = 0; qi < QPG; ++qi) {
            dA[qi] = half_allsum(dA[qi]);
            dB[qi] = half_allsum(dB[qi]);
        }

        float mraw = fmaxf(fmaxf(dA[0], dA[1]), fmaxf(dA[2], dA[3]));
        mraw = fmaxf(mraw, fmaxf(fmaxf(dB[0], dB[1]), fmaxf(dB[2], dB[3])));
        const float mx = mraw * SCALE;
        if (mx > m_run) {                // rare: deferred-max rescale (half-uniform)
            const float newm  = mx + RESCALE_MARGIN;
            const float alpha = exp2f((m_run - newm) * L2E);
            m_run = newm;
            bexp  = -m_run * L2E;
#pragma unroll
            for (int qi = 0; qi < QPG; ++qi) {
                e_i[qi] *= alpha;
                acc[qi].x *= alpha; acc[qi].y *= alpha;
                acc[qi].z *= alpha; acc[qi].w *= alpha;
            }
        }
#pragma unroll
        for (int qi = 0; qi < QPG; ++qi) {
            const float p1 = exp2f(fmaf(dA[qi], K1L2E, bexp));
            const float p2 = exp2f(fmaf(dB[qi], K1L2E, bexp));
            e_i[qi] += p1 + p2;
            acc[qi].x = fmaf(p2, v2.x, fmaf(p1, v1.x, acc[qi].x));
            acc[qi].y = fmaf(p2, v2.y, fmaf(p1, v1.y, acc[qi].y));
            acc[qi].z = fmaf(p2, v2.z, fmaf(p1, v1.z, acc[qi].z));
            acc[qi].w = fmaf(p2, v2.w, fmaf(p1, v1.w, acc[qi].w));
        }
    }
    if (t < ctx) {                       // peeled single-token tail
        const int off1 = bt_lds[t >> 4] * BLK_STRIDE + (t & 15) * HEAD_SIZE + d0;
        const float4 k1 = *reinterpret_cast<const float4*>(kbase + off1);
        const float4 v1 = *reinterpret_cast<const float4*>(vbase + off1);
        float dA[QPG];
#pragma unroll
        for (int qi = 0; qi < QPG; ++qi)
            dA[qi] = qf[qi].x*k1.x + qf[qi].y*k1.y + qf[qi].z*k1.z + qf[qi].w*k1.w;
#pragma unroll
        for (int qi = 0; qi < QPG; ++qi)
            dA[qi] = half_allsum(dA[qi]);
        const float mx = SCALE * fmaxf(fmaxf(dA[0], dA[1]), fmaxf(dA[2], dA[3]));
        if (mx > m_run) {
            const float newm  = mx + RESCALE_MARGIN;
            const float alpha = exp2f((m_run - newm) * L2E);
            m_run = newm;
            bexp  = -m_run * L2E;
#pragma unroll
            for (int qi = 0; qi < QPG; ++qi) {
                e_i[qi] *= alpha;
                acc[qi].x *= alpha; acc[qi].y *= alpha;
                acc[qi].z *= alpha; acc[qi].w *= alpha;
            }
        }
#pragma unroll
        for (int qi = 0; qi < QPG; ++qi) {
            const float p1 = exp2f(fmaf(dA[qi], K1L2E, bexp));
            e_i[qi] += p1;
            acc[qi].x = fmaf(p1, v1.x, acc[qi].x);
            acc[qi].y = fmaf(p1, v1.y, acc[qi].y);
            acc[qi].z = fmaf(p1, v1.z, acc[qi].z);
            acc[qi].w = fmaf(p1, v1.w, acc[qi].w);
        }
    }

    // merge the 8 local half-accumulators through LDS
    if (lane == 0) sm_m[accid] = m_run;
#pragma unroll
    for (int qi = 0; qi < QPG; ++qi) {
        if (lane == 0) sm_e[accid][qi] = e_i[qi];
        sm_acc[accid][qi][d0 + 0] = acc[qi].x;
        sm_acc[accid][qi][d0 + 1] = acc[qi].y;
        sm_acc[accid][qi][d0 + 2] = acc[qi].z;
        sm_acc[accid][qi][d0 + 3] = acc[qi].w;
    }
    __syncthreads();

    const int r = w * SPLIT + p;         // partial id 0..NPART-1
    float gm = NEG_BIG;
#pragma unroll
    for (int hh = 0; hh < 8; ++hh) gm = fmaxf(gm, sm_m[hh]);
    float sc[8];                          // hoisted: independent of (qi,d)
#pragma unroll
    for (int hh = 0; hh < 8; ++hh) sc[hh] = __expf(sm_m[hh] - gm);

    for (int pi = tid; pi < QPG * HEAD_SIZE; pi += 256) {
        const int qi = pi >> 7;
        const int d  = pi & (HEAD_SIZE - 1);
        float num = 0.f, den = 0.f;
#pragma unroll
        for (int hh = 0; hh < 8; ++hh) {
            num += sm_acc[hh][qi][d] * sc[hh];   // empty half: acc=0,e=0 -> no contrib
            den += sm_e[hh][qi] * sc[hh];
        }
        const size_t idx = (((size_t)r * S + s) * G + g) * QPG + qi;
        acc_ws[idx * HEAD_SIZE + d] = num;
        if (d == 0) { m_ws[idx] = gm; e_ws[idx] = den; }
    }
}

// Kernel 2: LSE combine over NPART partials. One block per (s,g).
__global__ __launch_bounds__(256)
void pa_reduce_kernel(const float* __restrict__ acc_ws,
                      const float* __restrict__ m_ws,
                      const float* __restrict__ e_ws,
                      float* __restrict__ out)
{
    const int bx = blockIdx.x;       // s*G + g
    const int s = bx / G, g = bx % G;
    const int tid = threadIdx.x;
    for (int pi = tid; pi < QPG * HEAD_SIZE; pi += 256) {
        const int qi = pi >> 7;
        const int d  = pi & (HEAD_SIZE - 1);
        float mw[NPART], ew[NPART];
        float gm = NEG_BIG;
#pragma unroll
        for (int r = 0; r < NPART; ++r) {
            const size_t idx = (((size_t)r * S + s) * G + g) * QPG + qi;
            mw[r] = m_ws[idx];
            ew[r] = e_ws[idx];
            gm = fmaxf(gm, mw[r]);
        }
        float num = 0.f, den = 0.f;
#pragma unroll
        for (int r = 0; r < NPART; ++r) {
            const float sc = __expf(mw[r] - gm);
            const size_t idx = (((size_t)r * S + s) * G + g) * QPG + qi;
            num += acc_ws[idx * HEAD_SIZE + d] * sc;
            den += ew[r] * sc;
        }
        out[((size_t)s * NUM_HEADS + g * QPG + qi) * HEAD_SIZE + d] = num / den;
    }
}

// Fallback fused single-kernel path (no workspace): kept for safety if ws_size
// is ever too small. One block per (s,g).
__global__ __launch_bounds__(256)
void pa_fused_kernel(const float* __restrict__ query,
                     const float* __restrict__ key_cache,
                     const float* __restrict__ value_cache,
                     const int* __restrict__ block_tables,
                     const int* __restrict__ context_lens,
                     float* __restrict__ out)
{
    const int bx = blockIdx.x;
    const int s = bx / G, g = bx % G;
    const int tid   = threadIdx.x;
    const int accid = tid >> 5;
    const int lane  = tid & 31;
    const int d0    = lane * 4;

    __shared__ int   bt_lds[MAX_BLOCKS];
    __shared__ float sm_m[8][QPG];
    __shared__ float sm_e[8][QPG];
    __shared__ float sm_acc[8][QPG][HEAD_SIZE];

    float4 qf[QPG];
#pragma unroll
    for (int qi = 0; qi < QPG; ++qi)
        qf[qi] = *reinterpret_cast<const float4*>(
            query + ((size_t)s * NUM_HEADS + g * QPG + qi) * HEAD_SIZE + d0);

    float  m_i[QPG], e_i[QPG];
    float4 acc[QPG];
#pragma unroll
    for (int qi = 0; qi < QPG; ++qi) {
        m_i[qi] = NEG_BIG; e_i[qi] = 0.f;
        acc[qi] = make_float4(0.f, 0.f, 0.f, 0.f);
    }

    for (int w = 0; w < W; ++w) {
        __syncthreads();
        if (tid < MAX_BLOCKS)
            bt_lds[tid] = block_tables[((size_t)w * S + s) * MAX_BLOCKS + tid];
        __syncthreads();
        const int ctx = context_lens[w * S + s];
        const float* kbase = key_cache   + (size_t)w * WG_STRIDE + (size_t)g * BLOCK_SZ * HEAD_SIZE;
        const float* vbase = value_cache + (size_t)w * WG_STRIDE + (size_t)g * BLOCK_SZ * HEAD_SIZE;
        for (int t = accid; t < ctx; t += 8) {
            const int off = bt_lds[t >> 4] * BLK_STRIDE + (t & 15) * HEAD_SIZE + d0;
            const float4 kx = *reinterpret_cast<const float4*>(kbase + off);
            const float4 vx = *reinterpret_cast<const float4*>(vbase + off);
            float dv[QPG];
#pragma unroll
            for (int qi = 0; qi < QPG; ++qi)
                dv[qi] = qf[qi].x*kx.x + qf[qi].y*kx.y + qf[qi].z*kx.z + qf[qi].w*kx.w;
#pragma unroll
            for (int qi = 0; qi < QPG; ++qi)
                dv[qi] = half_allsum(dv[qi]);
#pragma unroll
            for (int qi = 0; qi < QPG; ++qi) {
                const float lg    = dv[qi] * SCALE;
                const float mn    = fmaxf(m_i[qi], lg);
                const float alpha = __expf(m_i[qi] - mn);
                const float pp    = __expf(lg - mn);
                m_i[qi] = mn;
                e_i[qi] = e_i[qi] * alpha + pp;
                acc[qi].x = fmaf(acc[qi].x, alpha, pp * vx.x);
                acc[qi].y = fmaf(acc[qi].y, alpha, pp * vx.y);
                acc[qi].z = fmaf(acc[qi].z, alpha, pp * vx.z);
                acc[qi].w = fmaf(acc[qi].w, alpha, pp * vx.w);
            }
        }
    }

#pragma unroll
    for (int qi = 0; qi < QPG; ++qi) {
        if (lane == 0) { sm_m[accid][qi] = m_i[qi]; sm_e[accid][qi] = e_i[qi]; }
        sm_acc[accid][qi][d0 + 0] = acc[qi].x;
        sm_acc[accid][qi][d0 + 1] = acc[qi].y;
        sm_acc[accid][qi][d0 + 2] = acc[qi].z;
        sm_acc[accid][qi][d0 + 3] = acc[qi].w;
    }
    __syncthreads();

    for (int pi = tid; pi < QPG * HEAD_SIZE; pi += 256) {
        const int qi = pi >> 7;
        const int d  = pi & (HEAD_SIZE - 1);
        float gm = NEG_BIG;
#pragma unroll
        for (int hh = 0; hh < 8; ++hh) gm = fmaxf(gm, sm_m[hh][qi]);
        float num = 0.f, den = 0.f;
#pragma unroll
        for (int hh = 0; hh < 8; ++hh) {
            const float sc = __expf(sm_m[hh][qi] - gm);
            num += sm_acc[hh][qi][d] * sc;
            den += sm_e[hh][qi] * sc;
        }
        out[((size_t)s * NUM_HEADS + g * QPG + qi) * HEAD_SIZE + d] = num / den;
    }
}

extern "C" void kernel_launch(void* const* d_in, const int* in_sizes, int n_in,
                              void* d_out, int out_size, void* d_ws, size_t ws_size,
                              hipStream_t stream) {
    const float* query        = (const float*)d_in[0];
    const float* key_cache    = (const float*)d_in[1];
    const float* value_cache  = (const float*)d_in[2];
    const int*   block_tables = (const int*)d_in[3];
    const int*   context_lens = (const int*)d_in[4];
    float* out = (float*)d_out;

    const size_t n_acc   = (size_t)NPART * S * G * QPG * HEAD_SIZE;
    const size_t n_stats = (size_t)NPART * S * G * QPG;
    const size_t need    = (n_acc + 2 * n_stats) * sizeof(float);

    if (ws_size >= need) {
        float* acc_ws = (float*)d_ws;
        float* m_ws   = acc_ws + n_acc;
        float* e_ws   = m_ws + n_stats;
        pa_partial_kernel<<<W * S * G * SPLIT, 256, 0, stream>>>(
            query, key_cache, value_cache, block_tables, context_lens,
            acc_ws, m_ws, e_ws);
        pa_reduce_kernel<<<S * G, 256, 0, stream>>>(acc_ws, m_ws, e_ws, out);
    } else {
        pa_fused_kernel<<<S * G, 256, 0, stream>>>(
            query, key_cache, value_cache, block_tables, context_lens, out);
    }
}